// Round 1
// baseline (474.134 us; speedup 1.0000x reference)
//
#include <hip/hip_runtime.h>
#include <hip/hip_cooperative_groups.h>

namespace cg = cooperative_groups;

#define NN 5000
#define NE 40000
#define MAXGRID 512

typedef unsigned int u32;
typedef unsigned short u16;
typedef __fp16 h16x2 __attribute__((ext_vector_type(2)));
typedef _Float16 f16x8 __attribute__((ext_vector_type(8)));
typedef __attribute__((ext_vector_type(4))) float f32x4;

union AF { u32 u[4]; f16x8 v; uint4 q; };

__device__ __forceinline__ float siluf(float x) { return x / (1.f + __expf(-x)); }

__device__ __forceinline__ u32 f2bf_u(float f) {
  u32 x = __float_as_uint(f);
  return (x + 0x7FFFu + ((x >> 16) & 1u)) >> 16;  // RNE
}
__device__ __forceinline__ u16 f2bf(float f) { return (u16)f2bf_u(f); }
__device__ __forceinline__ float bf2f(u16 v) { return __uint_as_float(((u32)v) << 16); }
__device__ __forceinline__ u32 packbf2(float lo, float hi) {
  return f2bf_u(lo) | (f2bf_u(hi) << 16);
}
__device__ __forceinline__ u32 pkh2(float a, float b) {
  union { h16x2 h; u32 u; } r;
  r.h = __builtin_amdgcn_cvt_pkrtz(a, b);
  return r.u;
}
__device__ __forceinline__ u16 f2h(float v) {
  _Float16 h = (_Float16)v;
  return *(u16*)&h;
}
__device__ __forceinline__ void unpack8(uint4 q, float* f) {
  f[0] = __uint_as_float(q.x << 16); f[1] = __uint_as_float(q.x & 0xFFFF0000u);
  f[2] = __uint_as_float(q.y << 16); f[3] = __uint_as_float(q.y & 0xFFFF0000u);
  f[4] = __uint_as_float(q.z << 16); f[5] = __uint_as_float(q.z & 0xFFFF0000u);
  f[6] = __uint_as_float(q.w << 16); f[7] = __uint_as_float(q.w & 0xFFFF0000u);
}
__device__ __forceinline__ float dot8f(const float* h, const float* w, float init) {
  float a = init;
#pragma unroll
  for (int k = 0; k < 8; k++) a = fmaf(h[k], w[k], a);
  return a;
}
__device__ __forceinline__ void mlp8(const float* ea, const float* __restrict__ W0,
                                     const float* __restrict__ b0, float* h) {
#pragma unroll
  for (int j = 0; j < 8; j++) {
    float a = b0[j];
#pragma unroll
    for (int i = 0; i < 8; i++) a += ea[i] * W0[i*8 + j];
    h[j] = siluf(a);
  }
}
__device__ __forceinline__ AF mkfrag(float hs, const float* s) {
  AF a;
  a.u[0] = pkh2(hs*s[0], hs*s[1]);
  a.u[1] = pkh2(hs*s[2], hs*s[3]);
  a.u[2] = pkh2(hs*s[4], hs*s[5]);
  a.u[3] = pkh2(hs*s[6], hs*s[7]);
  return a;
}

struct Par {
  const float* coords; const int* atype; const int* eidx; const float* emb;
  const float* ipW0; const float* ipb0; const float* ipW1; const float* ipb1;
  const float* lyW0; const float* lyb0; const float* lyW1; const float* lyb1;
  const float* lyWs; const float* lyWv;
  const float* etW0; const float* etb0; const float* etW1; const float* etb1;
  const float* noW1; const float* noW2;
  float* sh; float* h_ip; float* h_ly; float* h_et;
  float* s1; float* v1soa; float* s2; float* v2;
  int* cur; int* perm; u16* msgA; u16* msgB; u16* lyT;
  float* outE; float* outN;
};

union SMem {
  u16 B2[18432];                                   // 36 KB weight image (conv phases)
  struct { uint4 WQ[640]; float BQ[640]; } e;      // 12.8 KB (e3 phase)
};

// One cooperative kernel, 5 phases separated by grid.sync().
// 2 blocks/CU co-resident (36 KB LDS, VGPR<=256 via launch_bounds).
__global__ __launch_bounds__(256, 2) void k_all(Par par) {
  __shared__ SMem sm;
  cg::grid_group grid = cg::this_grid();
  const int tid = threadIdx.x;
  const int bid = blockIdx.x;
  const int lane = tid & 63;
  const int m = lane & 15, q = lane >> 4, wid = tid >> 6;
  const int ngrid = (int)gridDim.x;
  const int ncb = ngrid - 16;       // conv1 compute blocks; last 16 do lyT transpose

  // ================= Phase 1: geometry + radial MLPs + perm + conv1 GEMM + lyT =================
  if (bid >= ncb) {
    int b = bid - ncb;              // 0..15
    int h = b >> 3;
    int t0 = (b & 7)*2304 + tid*9;
#pragma unroll
    for (int j = 0; j < 9; j++) {
      int t = t0 + j;               // 0..18431
      int kch = t >> 9, rem = t & 511;
      int col = rem >> 3, kk = rem & 7;
      int k = kch*8 + kk;
      int basec = (h == 0) ? ((col >> 5)*1024 + (col & 31))
                           : ((col < 32) ? (2048 + col) : (3072 + (col - 32)));
      float v = (k < 256) ? par.lyW1[(k >> 5)*4096 + basec + (k & 31)*32]
                          : par.lyb1[basec + (k - 256)*32];
      par.lyT[h*18432 + t] = f2h(v);
    }
  } else {
    {
      int col = tid & 63, pth = col >> 5, w = col & 31;
      int k0 = (tid >> 6) * 72;
      for (int k = k0; k < k0 + 72; k++) {
        float v = (k < 256) ? par.ipW1[(k >> 5)*2048 + pth*1024 + (k & 31)*32 + w]
                            : par.ipb1[pth*1024 + (k - 256)*32 + w];
        sm.B2[((k >> 3)*64 + col)*8 + (k & 7)] = f2h(v);
      }
    }
    // geometry for this block's tiles (iterations it = jj0, jj0+2, ...)
    if (tid < 128) {
      int w = (tid >> 4) & 3, mm = tid & 15, jj0 = tid >> 6;
      for (int it = jj0; ; it += 2) {
        int tile = bid*4 + w + it*(ncb*4);
        if (tile*16 >= NE) break;
        int e = tile*16 + mm;
        int s = par.eidx[e], d = par.eidx[NE + e];
        float vx = par.coords[d*3+0] - par.coords[s*3+0];
        float vy = par.coords[d*3+1] - par.coords[s*3+1];
        float vz = par.coords[d*3+2] - par.coords[s*3+2];
        float dist = sqrtf(vx*vx + vy*vy + vz*vz + 1e-12f);
        float inv = 1.f / dist;
        const float SQ3 = 1.7320508075688772f;
        par.sh[e*3+0] = SQ3 * vy * inv;   // e3nn (y,z,x)
        par.sh[e*3+1] = SQ3 * vz * inv;
        par.sh[e*3+2] = SQ3 * vx * inv;
        float ea[8];
        const float step = 5.f / 9.f;
#pragma unroll
        for (int jj = 0; jj < 8; jj++) {
          float diff = (dist - step * (float)(jj+1)) * (9.f / 5.f);
          ea[jj] = __expf(-diff*diff) * (1.f / 1.12f);
        }
        float h[8];
        mlp8(ea, par.ipW0, par.ipb0, h);
#pragma unroll
        for (int jj = 0; jj < 8; jj++) par.h_ip[e*8+jj] = h[jj];
        mlp8(ea, par.lyW0, par.lyb0, h);
#pragma unroll
        for (int jj = 0; jj < 8; jj++) par.h_ly[e*8+jj] = h[jj];
        mlp8(ea, par.etW0, par.etb0, h);
#pragma unroll
        for (int jj = 0; jj < 8; jj++) par.h_et[e*8+jj] = h[jj];
        int* cp = &par.cur[d];
        atomicCAS(cp, (int)0xAAAAAAAA, 0);   // first-touch zero (poison sentinel)
        int t = atomicAdd(cp, 1);
        if (t < 64) par.perm[d*64 + t] = e;
      }
    }
    __syncthreads();
    const float cs = 0.17677669529663687f;   // 1/sqrt(32)
    for (int tile = bid*4 + wid; tile*16 < NE; tile += ncb*4) {
      int e = tile*16 + m;
      int srow = par.atype[par.eidx[e]];
      float4 sA = *(const float4*)&par.emb[srow*32 + q*8];
      float4 sB = *(const float4*)&par.emb[srow*32 + q*8 + 4];
      float4 hA = *(const float4*)&par.h_ip[e*8];
      float4 hB = *(const float4*)&par.h_ip[e*8 + 4];
      float sf[8] = {sA.x,sA.y,sA.z,sA.w,sB.x,sB.y,sB.z,sB.w};
      float hf[8] = {hA.x,hA.y,hA.z,hA.w,hB.x,hB.y,hB.z,hB.w};
      f32x4 acc0 = {0.f,0.f,0.f,0.f}, acc1 = acc0, acc2 = acc0, acc3 = acc0;
#pragma unroll
      for (int ks = 0; ks < 9; ks++) {
        float hs = (ks < 8) ? hf[ks] : 1.f;
        AF a = mkfrag(hs, sf);
        int c2 = (ks*4 + q)*64;
        AF b0, b1f, b2, b3;
        b0.q  = *(const uint4*)&sm.B2[(c2 +  0 + m)*8];
        b1f.q = *(const uint4*)&sm.B2[(c2 + 16 + m)*8];
        b2.q  = *(const uint4*)&sm.B2[(c2 + 32 + m)*8];
        b3.q  = *(const uint4*)&sm.B2[(c2 + 48 + m)*8];
        acc0 = __builtin_amdgcn_mfma_f32_16x16x32_f16(a.v, b0.v,  acc0, 0, 0, 0);
        acc1 = __builtin_amdgcn_mfma_f32_16x16x32_f16(a.v, b1f.v, acc1, 0, 0, 0);
        acc2 = __builtin_amdgcn_mfma_f32_16x16x32_f16(a.v, b2.v,  acc2, 0, 0, 0);
        acc3 = __builtin_amdgcn_mfma_f32_16x16x32_f16(a.v, b3.v,  acc3, 0, 0, 0);
      }
#pragma unroll
      for (int r = 0; r < 4; r++) {
        int et = tile*16 + q*4 + r;
        u16* mp = par.msgA + (size_t)et*128;
        mp[m]      = f2bf(cs*acc0[r]);
        mp[16 + m] = f2bf(cs*acc1[r]);
        float s0v = par.sh[et*3+0], s1v = par.sh[et*3+1], s2v = par.sh[et*3+2];
        float m0 = cs*acc2[r], m1 = cs*acc3[r];
        mp[32 +      m] = f2bf(m0*s0v);
        mp[64 +      m] = f2bf(m0*s1v);
        mp[96 +      m] = f2bf(m0*s2v);
        mp[32 + 16 + m] = f2bf(m1*s0v);
        mp[64 + 16 + m] = f2bf(m1*s1v);
        mp[96 + 16 + m] = f2bf(m1*s2v);
      }
    }
  }
  __threadfence();
  grid.sync();

  // ================= Phase 2: gather1 (wave-autonomous, one wave per node) =================
  {
    int wg = (bid << 2) | wid;
    for (int n = wg; n < NN; n += ngrid*4) {
      int deg = min(par.cur[n], 64);
      int pv = par.perm[n*64 + lane];
      float a0 = 0.f, a1 = 0.f;
      for (int j = 0; j < deg; j++) {
        int e = __shfl(pv, j, 64);
        size_t off = (size_t)e*128 + lane;
        a0 += bf2f(par.msgA[off]);
        a1 += bf2f(par.msgA[off + 64]);
      }
      float inv = 1.f / (float)max(deg, 1);
      a0 *= inv; a1 *= inv;
      if (lane < 32) par.s1[n*32 + lane] = a0;
      else           par.v1soa[n*32 + (lane - 32)] = a0;      // i=0
      int i = 1 + (lane >> 5), w = lane & 31;
      par.v1soa[i*160000 + n*32 + w] = a1;                    // i=1,2
    }
  }
  __threadfence();
  grid.sync();

  // ================= Phase 3: conv2 (f16 MFMA, two half-grids) =================
  {
    const int half = ngrid >> 1;
    const bool scalarHalf = bid < half;
    int blk = scalarHalf ? bid : bid - half;
    const uint4* src4 = (const uint4*)(par.lyT + (scalarHalf ? 0 : 18432));
    uint4* dst4 = (uint4*)sm.B2;
    for (int t = tid; t < 2304; t += 256) dst4[t] = src4[t];
    __syncthreads();
    const float c = 0.125f;  // 1/sqrt(64)
    for (int tile = blk*4 + wid; tile*16 < NE; tile += half*4) {
      int e = tile*16 + m;
      int srcn = par.eidx[e];
      float4 hA = *(const float4*)&par.h_ly[e*8];
      float4 hB = *(const float4*)&par.h_ly[e*8 + 4];
      float hf[8] = {hA.x,hA.y,hA.z,hA.w,hB.x,hB.y,hB.z,hB.w};

      if (scalarHalf) {
        float4 sA = *(const float4*)&par.s1[srcn*32 + q*8];
        float4 sB = *(const float4*)&par.s1[srcn*32 + q*8 + 4];
        float sf[8] = {sA.x,sA.y,sA.z,sA.w,sB.x,sB.y,sB.z,sB.w};
        f32x4 acc0 = {0.f,0.f,0.f,0.f}, acc1 = acc0, acc2 = acc0, acc3 = acc0;
#pragma unroll
        for (int ks = 0; ks < 9; ks++) {
          float hs = (ks < 8) ? hf[ks] : 1.f;
          AF a = mkfrag(hs, sf);
          int c2 = (ks*4 + q)*64;
          AF b0, b1f, b2, b3;
          b0.q  = *(const uint4*)&sm.B2[(c2 +  0 + m)*8];
          b1f.q = *(const uint4*)&sm.B2[(c2 + 16 + m)*8];
          b2.q  = *(const uint4*)&sm.B2[(c2 + 32 + m)*8];
          b3.q  = *(const uint4*)&sm.B2[(c2 + 48 + m)*8];
          acc0 = __builtin_amdgcn_mfma_f32_16x16x32_f16(a.v, b0.v,  acc0, 0, 0, 0);
          acc1 = __builtin_amdgcn_mfma_f32_16x16x32_f16(a.v, b1f.v, acc1, 0, 0, 0);
          acc2 = __builtin_amdgcn_mfma_f32_16x16x32_f16(a.v, b2.v,  acc2, 0, 0, 0);
          acc3 = __builtin_amdgcn_mfma_f32_16x16x32_f16(a.v, b3.v,  acc3, 0, 0, 0);
        }
#pragma unroll
        for (int r = 0; r < 4; r++) {
          int et = tile*16 + q*4 + r;
          u16* mp = par.msgA + (size_t)et*128;
          mp[m]      = f2bf(c*acc0[r]);
          mp[16 + m] = f2bf(c*acc1[r]);
          float s0v = par.sh[et*3+0], s1v = par.sh[et*3+1], s2v = par.sh[et*3+2];
          float m0 = c*acc2[r], m1 = c*acc3[r];
          mp[32 +      m] = f2bf(m0*s0v);
          mp[64 +      m] = f2bf(m0*s1v);
          mp[96 +      m] = f2bf(m0*s2v);
          mp[32 + 16 + m] = f2bf(m1*s0v);
          mp[64 + 16 + m] = f2bf(m1*s1v);
          mp[96 + 16 + m] = f2bf(m1*s2v);
        }
      } else {
        const float is3 = 0.5773502691896258f;
        float vf[3][8];
#pragma unroll
        for (int i = 0; i < 3; i++) {
          float4 aa = *(const float4*)&par.v1soa[i*160000 + srcn*32 + q*8];
          float4 bb = *(const float4*)&par.v1soa[i*160000 + srcn*32 + q*8 + 4];
          vf[i][0]=aa.x; vf[i][1]=aa.y; vf[i][2]=aa.z; vf[i][3]=aa.w;
          vf[i][4]=bb.x; vf[i][5]=bb.y; vf[i][6]=bb.z; vf[i][7]=bb.w;
        }
        float es0 = par.sh[e*3+0], es1 = par.sh[e*3+1], es2 = par.sh[e*3+2];
        float df[8];
#pragma unroll
        for (int j = 0; j < 8; j++)
          df[j] = (vf[0][j]*es0 + vf[1][j]*es1 + vf[2][j]*es2) * is3;
        f32x4 z = {0.f,0.f,0.f,0.f};
        f32x4 aV00 = z, aV01 = z, aV10 = z, aV11 = z, aV20 = z, aV21 = z, aD0 = z, aD1 = z;
#pragma unroll
        for (int ks = 0; ks < 9; ks++) {
          float hs = (ks < 8) ? hf[ks] : 1.f;
          int c2 = (ks*4 + q)*64;
          AF b0, b1f, b2, b3;
          b0.q  = *(const uint4*)&sm.B2[(c2 +  0 + m)*8];
          b1f.q = *(const uint4*)&sm.B2[(c2 + 16 + m)*8];
          b2.q  = *(const uint4*)&sm.B2[(c2 + 32 + m)*8];
          b3.q  = *(const uint4*)&sm.B2[(c2 + 48 + m)*8];
          AF a0 = mkfrag(hs, vf[0]);
          AF a1 = mkfrag(hs, vf[1]);
          AF a2 = mkfrag(hs, vf[2]);
          AF ad = mkfrag(hs, df);
          aV00 = __builtin_amdgcn_mfma_f32_16x16x32_f16(a0.v, b0.v,  aV00, 0, 0, 0);
          aV01 = __builtin_amdgcn_mfma_f32_16x16x32_f16(a0.v, b1f.v, aV01, 0, 0, 0);
          aV10 = __builtin_amdgcn_mfma_f32_16x16x32_f16(a1.v, b0.v,  aV10, 0, 0, 0);
          aV11 = __builtin_amdgcn_mfma_f32_16x16x32_f16(a1.v, b1f.v, aV11, 0, 0, 0);
          aV20 = __builtin_amdgcn_mfma_f32_16x16x32_f16(a2.v, b0.v,  aV20, 0, 0, 0);
          aV21 = __builtin_amdgcn_mfma_f32_16x16x32_f16(a2.v, b1f.v, aV21, 0, 0, 0);
          aD0  = __builtin_amdgcn_mfma_f32_16x16x32_f16(ad.v, b2.v,  aD0,  0, 0, 0);
          aD1  = __builtin_amdgcn_mfma_f32_16x16x32_f16(ad.v, b3.v,  aD1,  0, 0, 0);
        }
#pragma unroll
        for (int r = 0; r < 4; r++) {
          int et = tile*16 + q*4 + r;
          u16* mp = par.msgB + (size_t)et*128;
          mp[m]      = f2bf(c*aD0[r]);
          mp[16 + m] = f2bf(c*aD1[r]);
          mp[32 +      m] = f2bf(c*aV00[r]);
          mp[32 + 16 + m] = f2bf(c*aV01[r]);
          mp[64 +      m] = f2bf(c*aV10[r]);
          mp[64 + 16 + m] = f2bf(c*aV11[r]);
          mp[96 +      m] = f2bf(c*aV20[r]);
          mp[96 + 16 + m] = f2bf(c*aV21[r]);
        }
      }
    }
  }
  __threadfence();
  grid.sync();

  // ========== Phase 4: gather2 + self-interaction + node MLP (wave-autonomous) ==========
  {
    const float lc = 0.17677669529663687f;   // 1/sqrt(32)
    const float i32c = 0.17677669529663687f;
    const float i13c = 0.2773500981126146f;  // 1/sqrt(13)
    int wg = (bid << 2) | wid;
    int c13 = (lane < 13) ? lane : 0;
    for (int n = wg; n < NN; n += ngrid*4) {
      int deg = min(par.cur[n], 64);
      int pv = par.perm[n*64 + lane];
      float a0 = 0.f, a1 = 0.f;
      for (int j = 0; j < deg; j++) {
        int e = __shfl(pv, j, 64);
        size_t off = (size_t)e*128 + lane;
        a0 += bf2f(par.msgA[off])      + bf2f(par.msgB[off]);
        a1 += bf2f(par.msgA[off + 64]) + bf2f(par.msgB[off + 64]);
      }
      float inv = 1.f / (float)max(deg, 1);
      a0 *= inv; a1 *= inv;
      float s2v = 0.f;
      if (lane < 32) {
        float ss = 0.f;
#pragma unroll 8
        for (int u = 0; u < 32; u++) ss += par.s1[n*32 + u] * par.lyWs[u*32 + lane];
        s2v = a0 + lc*ss;
        par.s2[n*32 + lane] = s2v;
      } else {
        int w0 = lane & 31;
        float sv = 0.f;
#pragma unroll 8
        for (int u = 0; u < 32; u++) sv += par.v1soa[n*32 + u] * par.lyWv[u*32 + w0];
        par.v2[n*96 + w0*3 + 0] = a0 + lc*sv;
      }
      {
        int i = 1 + (lane >> 5), w0 = lane & 31;
        float sv = 0.f;
#pragma unroll 8
        for (int u = 0; u < 32; u++) sv += par.v1soa[i*160000 + n*32 + u] * par.lyWv[u*32 + w0];
        par.v2[n*96 + w0*3 + i] = a1 + lc*sv;
      }
      // node MLP via in-wave broadcast of s2 (lanes 0..31 hold it)
      float a = 0.f;
#pragma unroll 8
      for (int u = 0; u < 32; u++) a += __shfl(s2v, u, 64) * par.noW1[u*13 + c13];
      float hv = siluf(a * i32c);
      float o = 0.f;
#pragma unroll
      for (int j = 0; j < 13; j++) o += __shfl(hv, j, 64) * par.noW2[j*13 + c13];
      if (lane < 13) par.outN[n*13 + lane] = o * i13c;
    }
  }
  __threadfence();
  grid.sync();

  // ================= Phase 5: edge output TP -> 5x0e =================
  {
    for (int t = tid; t < 640; t += 256) {
      int u = t & 31, pw = t >> 5, p2 = pw / 5, w = pw - p2*5;
      int col = p2*160 + u*5 + w;
      const float* s = par.etW1 + col;
      uint4 qq;
      qq.x = packbf2(s[0],      s[640]);
      qq.y = packbf2(s[1280],   s[1920]);
      qq.z = packbf2(s[2560],   s[3200]);
      qq.w = packbf2(s[3840],   s[4480]);
      sm.e.WQ[t] = qq;
      sm.e.BQ[t] = par.etb1[col];
    }
    __syncthreads();
    const int g = tid >> 5, tw = tid & 31;
    const float ce = 0.08838834764831845f;   // 1/sqrt(128)
    const float is3 = 0.5773502691896258f;
    for (int pr = bid*8 + g; pr*2 < NE; pr += ngrid*8) {
      int e0 = pr*2, e1 = e0 + 1;
      float h0[8], h1[8];
      {
        float4 qa = *(const float4*)&par.h_et[e0*8];
        float4 qb = *(const float4*)&par.h_et[e0*8+4];
        h0[0]=qa.x; h0[1]=qa.y; h0[2]=qa.z; h0[3]=qa.w;
        h0[4]=qb.x; h0[5]=qb.y; h0[6]=qb.z; h0[7]=qb.w;
        float4 qc = *(const float4*)&par.h_et[e1*8];
        float4 qd = *(const float4*)&par.h_et[e1*8+4];
        h1[0]=qc.x; h1[1]=qc.y; h1[2]=qc.z; h1[3]=qc.w;
        h1[4]=qd.x; h1[5]=qd.y; h1[6]=qd.z; h1[7]=qd.w;
      }
      int sA = par.eidx[e0], dA = par.eidx[NE+e0];
      int sB = par.eidx[e1], dB = par.eidx[NE+e1];
      float sa0 = par.sh[e0*3+0], sa1 = par.sh[e0*3+1], sa2 = par.sh[e0*3+2];
      float sb0 = par.sh[e1*3+0], sb1 = par.sh[e1*3+1], sb2 = par.sh[e1*3+2];
      float c00 = par.s2[sA*32 + tw];
      float c01 = (par.v2[sA*96+tw*3+0]*sa0 + par.v2[sA*96+tw*3+1]*sa1 + par.v2[sA*96+tw*3+2]*sa2) * is3;
      float c02 = par.s2[dA*32 + tw];
      float c03 = (par.v2[dA*96+tw*3+0]*sa0 + par.v2[dA*96+tw*3+1]*sa1 + par.v2[dA*96+tw*3+2]*sa2) * is3;
      float c10 = par.s2[sB*32 + tw];
      float c11 = (par.v2[sB*96+tw*3+0]*sb0 + par.v2[sB*96+tw*3+1]*sb1 + par.v2[sB*96+tw*3+2]*sb2) * is3;
      float c12 = par.s2[dB*32 + tw];
      float c13 = (par.v2[dB*96+tw*3+0]*sb0 + par.v2[dB*96+tw*3+1]*sb1 + par.v2[dB*96+tw*3+2]*sb2) * is3;
      float part0[5] = {0,0,0,0,0};
      float part1[5] = {0,0,0,0,0};
#pragma unroll
      for (int pp = 0; pp < 4; pp++) {
        float cp0 = (pp==0) ? c00 : (pp==1) ? c01 : (pp==2) ? c02 : c03;
        float cp1 = (pp==0) ? c10 : (pp==1) ? c11 : (pp==2) ? c12 : c13;
#pragma unroll
        for (int w = 0; w < 5; w++) {
          int idx = (pp*5 + w)*32 + tw;
          float f[8];
          unpack8(sm.e.WQ[idx], f);
          float bv = sm.e.BQ[idx];
          part0[w] = fmaf(cp0, dot8f(h0, f, bv), part0[w]);
          part1[w] = fmaf(cp1, dot8f(h1, f, bv), part1[w]);
        }
      }
#pragma unroll
      for (int off = 16; off > 0; off >>= 1)
#pragma unroll
        for (int w = 0; w < 5; w++) {
          part0[w] += __shfl_xor(part0[w], off, 32);
          part1[w] += __shfl_xor(part1[w], off, 32);
        }
      float outv = 0.f;
#pragma unroll
      for (int w = 0; w < 5; w++) {
        if (tw == w)     outv = part0[w];
        if (tw == 5 + w) outv = part1[w];
      }
      if (tw < 10) par.outE[e0*5 + tw] = ce * outv;
    }
  }
}

extern "C" void kernel_launch(void* const* d_in, const int* in_sizes, int n_in,
                              void* d_out, int out_size, void* d_ws, size_t ws_size,
                              hipStream_t stream) {
  (void)in_sizes; (void)n_in; (void)out_size; (void)ws_size;
  float* ws = (float*)d_ws;
  Par par;
  par.coords = (const float*)d_in[0];
  par.atype  = (const int*)d_in[1];
  par.eidx   = (const int*)d_in[2];
  par.emb    = (const float*)d_in[3];
  par.ipW0 = (const float*)d_in[4];
  par.ipb0 = (const float*)d_in[5];
  par.ipW1 = (const float*)d_in[6];
  par.ipb1 = (const float*)d_in[7];
  par.lyW0 = (const float*)d_in[8];
  par.lyb0 = (const float*)d_in[9];
  par.lyW1 = (const float*)d_in[10];
  par.lyb1 = (const float*)d_in[11];
  par.lyWs = (const float*)d_in[12];
  par.lyWv = (const float*)d_in[13];
  par.etW0 = (const float*)d_in[14];
  par.etb0 = (const float*)d_in[15];
  par.etW1 = (const float*)d_in[16];
  par.etb1 = (const float*)d_in[17];
  par.noW1 = (const float*)d_in[18];
  par.noW2 = (const float*)d_in[19];
  par.sh    = ws;                        // E*3
  par.h_ip  = ws + 120000;               // E*8
  par.h_ly  = ws + 440000;               // E*8
  par.h_et  = ws + 760000;               // E*8
  par.s1    = ws + 1240000;              // N*32
  par.v1soa = ws + 1400000;              // 3 x 160000 (SoA)
  par.s2    = ws + 1880000;              // N*32
  par.v2    = ws + 2040000;              // N*96 (AoS)
  par.cur   = (int*)(ws + 2520000);      // N ints (poison sentinel, CAS-zeroed)
  par.perm  = (int*)(ws + 2525000);      // N*64 ints
  par.msgA  = (u16*)(ws + 2845000);      // E*128 bf16
  par.msgB  = (u16*)(ws + 5405000);      // E*128 bf16
  par.lyT   = (u16*)(ws + 7965000);      // 2*18432 f16 (pre-transposed conv2 weights)
  par.outE  = (float*)d_out;             // E*5
  par.outN  = (float*)d_out + NE*5;      // N*13

  // Cooperative grid sized so co-residency is guaranteed (cached; query once).
  static int grid_sz = 0;
  if (grid_sz == 0) {
    int nb = 0;
    hipOccupancyMaxActiveBlocksPerMultiprocessor(&nb, k_all, 256, 0);
    int dev = 0;
    hipGetDevice(&dev);
    hipDeviceProp_t prop;
    hipGetDeviceProperties(&prop, dev);
    int g = nb * prop.multiProcessorCount;
    if (g > MAXGRID) g = MAXGRID;
    if (g < 32) g = 32;
    grid_sz = g;
  }
  void* args[] = { (void*)&par };
  hipLaunchCooperativeKernel((void*)k_all, dim3(grid_sz), dim3(256), args, 0, stream);
}

// Round 2
// 177.866 us; speedup vs baseline: 2.6657x; 2.6657x over previous
//
#include <hip/hip_runtime.h>

#define NN 5000
#define NE 40000
#define HB 625   // conv1 compute blocks: 625*4 waves = 2500 tiles, 1 tile/wave

typedef unsigned int u32;
typedef unsigned short u16;
typedef __fp16 h16x2 __attribute__((ext_vector_type(2)));
typedef _Float16 f16x8 __attribute__((ext_vector_type(8)));
typedef __attribute__((ext_vector_type(4))) float f32x4;

union AF { u32 u[4]; f16x8 v; uint4 q; };

__device__ __forceinline__ float siluf(float x) { return x / (1.f + __expf(-x)); }

__device__ __forceinline__ u32 f2bf_u(float f) {
  u32 x = __float_as_uint(f);
  return (x + 0x7FFFu + ((x >> 16) & 1u)) >> 16;  // RNE
}
__device__ __forceinline__ u16 f2bf(float f) { return (u16)f2bf_u(f); }
__device__ __forceinline__ float bf2f(u16 v) { return __uint_as_float(((u32)v) << 16); }
__device__ __forceinline__ u32 packbf2(float lo, float hi) {
  return f2bf_u(lo) | (f2bf_u(hi) << 16);
}
__device__ __forceinline__ u32 pkh2(float a, float b) {
  union { h16x2 h; u32 u; } r;
  r.h = __builtin_amdgcn_cvt_pkrtz(a, b);
  return r.u;
}
__device__ __forceinline__ u16 f2h(float v) {
  _Float16 h = (_Float16)v;
  return *(u16*)&h;
}
__device__ __forceinline__ void unpack8(uint4 q, float* f) {
  f[0] = __uint_as_float(q.x << 16); f[1] = __uint_as_float(q.x & 0xFFFF0000u);
  f[2] = __uint_as_float(q.y << 16); f[3] = __uint_as_float(q.y & 0xFFFF0000u);
  f[4] = __uint_as_float(q.z << 16); f[5] = __uint_as_float(q.z & 0xFFFF0000u);
  f[6] = __uint_as_float(q.w << 16); f[7] = __uint_as_float(q.w & 0xFFFF0000u);
}
__device__ __forceinline__ float dot8f(const float* h, const float* w, float init) {
  float a = init;
#pragma unroll
  for (int k = 0; k < 8; k++) a = fmaf(h[k], w[k], a);
  return a;
}
__device__ __forceinline__ void mlp8(const float* ea, const float* __restrict__ W0,
                                     const float* __restrict__ b0, float* h) {
#pragma unroll
  for (int j = 0; j < 8; j++) {
    float a = b0[j];
#pragma unroll
    for (int i = 0; i < 8; i++) a += ea[i] * W0[i*8 + j];
    h[j] = siluf(a);
  }
}
__device__ __forceinline__ AF mkfrag(float hs, const float* s) {
  AF a;
  a.u[0] = pkh2(hs*s[0], hs*s[1]);
  a.u[1] = pkh2(hs*s[2], hs*s[3]);
  a.u[2] = pkh2(hs*s[4], hs*s[5]);
  a.u[3] = pkh2(hs*s[6], hs*s[7]);
  return a;
}

// ---- conv1 fused: geometry + 3 radial MLPs + bucket fill + f16 MFMA GEMM.
// HB blocks compute; blocks [HB, HB+16) pre-transpose lyW1 into the conv2 LDS image.
// With HB=625 each block's prepass edges == its GEMM edges, so h_ip/sh/atype
// ride in LDS and never round-trip through global for the GEMM phase.
__global__ __launch_bounds__(256) void k_conv1g(
    const float* __restrict__ coords, const int* __restrict__ eidx,
    const float* __restrict__ emb, const int* __restrict__ atype,
    const float* __restrict__ ipW0, const float* __restrict__ ipb0,
    const float* __restrict__ lyW0, const float* __restrict__ lyb0,
    const float* __restrict__ etW0, const float* __restrict__ etb0,
    const float* __restrict__ W1, const float* __restrict__ b1,
    const float* __restrict__ lyW1, const float* __restrict__ lyb1,
    float* __restrict__ sh, float* __restrict__ h_ly, float* __restrict__ h_et,
    int* __restrict__ cur, int* __restrict__ perm,
    u16* __restrict__ msg, u16* __restrict__ lyT) {
  if (blockIdx.x >= HB) {
    int b = blockIdx.x - HB;        // 0..15
    int h = b >> 3;
    int t0 = (b & 7)*2304 + threadIdx.x*9;
#pragma unroll
    for (int j = 0; j < 9; j++) {
      int t = t0 + j;               // 0..18431
      int kch = t >> 9, rem = t & 511;
      int col = rem >> 3, kk = rem & 7;
      int k = kch*8 + kk;
      int basec = (h == 0) ? ((col >> 5)*1024 + (col & 31))
                           : ((col < 32) ? (2048 + col) : (3072 + (col - 32)));
      float v = (k < 256) ? lyW1[(k >> 5)*4096 + basec + (k & 31)*32]
                          : lyb1[basec + (k - 256)*32];
      lyT[h*18432 + t] = f2h(v);
    }
    return;
  }
  __shared__ __align__(16) u16 B2[36*64*8];   // 36 KB
  __shared__ float hl[64][9];                 // h_ip for block's 64 edges (padded)
  __shared__ float shl[64][4];                // sh for block's 64 edges
  __shared__ int   sAl[64];                   // atype[src] for block's 64 edges
  {
    int col = threadIdx.x & 63, pth = col >> 5, w = col & 31;
    int k0 = (threadIdx.x >> 6) * 72;
    for (int k = k0; k < k0 + 72; k++) {
      float v = (k < 256) ? W1[(k >> 5)*2048 + pth*1024 + (k & 31)*32 + w]
                          : b1[pth*1024 + (k - 256)*32 + w];
      B2[((k >> 3)*64 + col)*8 + (k & 7)] = f2h(v);
    }
  }
  // geometry pre-pass: 64 threads, 1 edge each (block's 4 tiles x 16 edges)
  if (threadIdx.x < 64) {
    int idx = threadIdx.x;
    int w = (idx >> 4) & 3, m = idx & 15;
    int tile = blockIdx.x*4 + w;
    int e = tile*16 + m;
    int s = eidx[e], d = eidx[NE + e];
    float vx = coords[d*3+0] - coords[s*3+0];
    float vy = coords[d*3+1] - coords[s*3+1];
    float vz = coords[d*3+2] - coords[s*3+2];
    float dist = sqrtf(vx*vx + vy*vy + vz*vz + 1e-12f);
    float inv = 1.f / dist;
    const float SQ3 = 1.7320508075688772f;
    float s0 = SQ3 * vy * inv;   // e3nn (y,z,x)
    float s1 = SQ3 * vz * inv;
    float s2 = SQ3 * vx * inv;
    sh[e*3+0] = s0; sh[e*3+1] = s1; sh[e*3+2] = s2;
    shl[idx][0] = s0; shl[idx][1] = s1; shl[idx][2] = s2;
    sAl[idx] = atype[s];
    float ea[8];
    const float step = 5.f / 9.f;
#pragma unroll
    for (int jj = 0; jj < 8; jj++) {
      float diff = (dist - step * (float)(jj+1)) * (9.f / 5.f);
      ea[jj] = __expf(-diff*diff) * (1.f / 1.12f);
    }
    float h[8];
    mlp8(ea, ipW0, ipb0, h);
#pragma unroll
    for (int jj = 0; jj < 8; jj++) hl[idx][jj] = h[jj];
    mlp8(ea, lyW0, lyb0, h);
    { float4 f0 = {h[0],h[1],h[2],h[3]}, f1 = {h[4],h[5],h[6],h[7]};
      *(float4*)&h_ly[e*8] = f0; *(float4*)&h_ly[e*8+4] = f1; }
    mlp8(ea, etW0, etb0, h);
    { float4 f0 = {h[0],h[1],h[2],h[3]}, f1 = {h[4],h[5],h[6],h[7]};
      *(float4*)&h_et[e*8] = f0; *(float4*)&h_et[e*8+4] = f1; }
    int* cp = &cur[d];
    atomicCAS(cp, (int)0xAAAAAAAA, 0);   // first-touch zero (poison sentinel)
    int t = atomicAdd(cp, 1);
    if (t < 64) perm[d*64 + t] = e;
  }
  __syncthreads();
  int lane = threadIdx.x & 63;
  int m = lane & 15, q = lane >> 4, wid = threadIdx.x >> 6;
  const float cs = 0.17677669529663687f;   // 1/sqrt(32)
  int tile = blockIdx.x*4 + wid;           // exactly one tile per wave
  {
    int le = wid*16 + m;
    int srow = sAl[le];
    float4 sA = *(const float4*)&emb[srow*32 + q*8];
    float4 sB = *(const float4*)&emb[srow*32 + q*8 + 4];
    float sf[8] = {sA.x,sA.y,sA.z,sA.w,sB.x,sB.y,sB.z,sB.w};
    float hf[8];
#pragma unroll
    for (int k = 0; k < 8; k++) hf[k] = hl[le][k];
    f32x4 acc0 = {0.f,0.f,0.f,0.f}, acc1 = acc0, acc2 = acc0, acc3 = acc0;
#pragma unroll
    for (int ks = 0; ks < 9; ks++) {
      float hs = (ks < 8) ? hf[ks] : 1.f;
      AF a = mkfrag(hs, sf);
      int c2 = (ks*4 + q)*64;
      AF b0, b1f, b2, b3;
      b0.q  = *(const uint4*)&B2[(c2 +  0 + m)*8];
      b1f.q = *(const uint4*)&B2[(c2 + 16 + m)*8];
      b2.q  = *(const uint4*)&B2[(c2 + 32 + m)*8];
      b3.q  = *(const uint4*)&B2[(c2 + 48 + m)*8];
      acc0 = __builtin_amdgcn_mfma_f32_16x16x32_f16(a.v, b0.v,  acc0, 0, 0, 0);
      acc1 = __builtin_amdgcn_mfma_f32_16x16x32_f16(a.v, b1f.v, acc1, 0, 0, 0);
      acc2 = __builtin_amdgcn_mfma_f32_16x16x32_f16(a.v, b2.v,  acc2, 0, 0, 0);
      acc3 = __builtin_amdgcn_mfma_f32_16x16x32_f16(a.v, b3.v,  acc3, 0, 0, 0);
    }
#pragma unroll
    for (int r = 0; r < 4; r++) {
      int lr = wid*16 + q*4 + r;
      int et = tile*16 + q*4 + r;
      u16* mp = msg + (size_t)et*128;
      mp[m]      = f2bf(cs*acc0[r]);
      mp[16 + m] = f2bf(cs*acc1[r]);
      float s0v = shl[lr][0], s1v = shl[lr][1], s2v = shl[lr][2];
      float m0 = cs*acc2[r], m1 = cs*acc3[r];
      mp[32 +      m] = f2bf(m0*s0v);
      mp[64 +      m] = f2bf(m0*s1v);
      mp[96 +      m] = f2bf(m0*s2v);
      mp[32 + 16 + m] = f2bf(m1*s0v);
      mp[64 + 16 + m] = f2bf(m1*s1v);
      mp[96 + 16 + m] = f2bf(m1*s2v);
    }
  }
}

// ---- conv2 (f16), staging = coalesced copy of pre-transposed lyT; 1 tile/wave ----
__global__ __launch_bounds__(256) void k_conv2(
    const float* __restrict__ hE, const float* __restrict__ sh,
    const float* __restrict__ s1, const float* __restrict__ v1soa,
    const int* __restrict__ eidx, const u16* __restrict__ lyT,
    u16* __restrict__ msgA, u16* __restrict__ msgB) {
  __shared__ __align__(16) u16 B2[36*64*8];
  const bool scalarHalf = blockIdx.x < HB;
  int blk = scalarHalf ? blockIdx.x : blockIdx.x - HB;
  {
    const uint4* src4 = (const uint4*)(lyT + (scalarHalf ? 0 : 18432));
    uint4* dst4 = (uint4*)B2;
    for (int t = threadIdx.x; t < 2304; t += 256) dst4[t] = src4[t];
  }
  __syncthreads();
  int lane = threadIdx.x & 63;
  int m = lane & 15, q = lane >> 4, wid = threadIdx.x >> 6;
  const float c = 0.125f;  // 1/sqrt(64)
  int tile = blk*4 + wid;  // exactly one tile per wave
  {
    int e = tile*16 + m;
    int srcn = eidx[e];
    float4 hA = *(const float4*)&hE[e*8];
    float4 hB = *(const float4*)&hE[e*8 + 4];
    float hf[8] = {hA.x,hA.y,hA.z,hA.w,hB.x,hB.y,hB.z,hB.w};

    if (scalarHalf) {
      float4 sA = *(const float4*)&s1[srcn*32 + q*8];
      float4 sB = *(const float4*)&s1[srcn*32 + q*8 + 4];
      float sf[8] = {sA.x,sA.y,sA.z,sA.w,sB.x,sB.y,sB.z,sB.w};
      f32x4 acc0 = {0.f,0.f,0.f,0.f}, acc1 = acc0, acc2 = acc0, acc3 = acc0;
#pragma unroll
      for (int ks = 0; ks < 9; ks++) {
        float hs = (ks < 8) ? hf[ks] : 1.f;
        AF a = mkfrag(hs, sf);
        int c2 = (ks*4 + q)*64;
        AF b0, b1f, b2, b3;
        b0.q  = *(const uint4*)&B2[(c2 +  0 + m)*8];
        b1f.q = *(const uint4*)&B2[(c2 + 16 + m)*8];
        b2.q  = *(const uint4*)&B2[(c2 + 32 + m)*8];
        b3.q  = *(const uint4*)&B2[(c2 + 48 + m)*8];
        acc0 = __builtin_amdgcn_mfma_f32_16x16x32_f16(a.v, b0.v,  acc0, 0, 0, 0);
        acc1 = __builtin_amdgcn_mfma_f32_16x16x32_f16(a.v, b1f.v, acc1, 0, 0, 0);
        acc2 = __builtin_amdgcn_mfma_f32_16x16x32_f16(a.v, b2.v,  acc2, 0, 0, 0);
        acc3 = __builtin_amdgcn_mfma_f32_16x16x32_f16(a.v, b3.v,  acc3, 0, 0, 0);
      }
#pragma unroll
      for (int r = 0; r < 4; r++) {
        int et = tile*16 + q*4 + r;
        u16* mp = msgA + (size_t)et*128;
        mp[m]      = f2bf(c*acc0[r]);
        mp[16 + m] = f2bf(c*acc1[r]);
        float s0v = sh[et*3+0], s1v = sh[et*3+1], s2v = sh[et*3+2];
        float m0 = c*acc2[r], m1 = c*acc3[r];
        mp[32 +      m] = f2bf(m0*s0v);
        mp[64 +      m] = f2bf(m0*s1v);
        mp[96 +      m] = f2bf(m0*s2v);
        mp[32 + 16 + m] = f2bf(m1*s0v);
        mp[64 + 16 + m] = f2bf(m1*s1v);
        mp[96 + 16 + m] = f2bf(m1*s2v);
      }
    } else {
      const float is3 = 0.5773502691896258f;
      float vf[3][8];
#pragma unroll
      for (int i = 0; i < 3; i++) {
        float4 aa = *(const float4*)&v1soa[i*160000 + srcn*32 + q*8];
        float4 bb = *(const float4*)&v1soa[i*160000 + srcn*32 + q*8 + 4];
        vf[i][0]=aa.x; vf[i][1]=aa.y; vf[i][2]=aa.z; vf[i][3]=aa.w;
        vf[i][4]=bb.x; vf[i][5]=bb.y; vf[i][6]=bb.z; vf[i][7]=bb.w;
      }
      float es0 = sh[e*3+0], es1 = sh[e*3+1], es2 = sh[e*3+2];
      float df[8];
#pragma unroll
      for (int j = 0; j < 8; j++)
        df[j] = (vf[0][j]*es0 + vf[1][j]*es1 + vf[2][j]*es2) * is3;
      f32x4 z = {0.f,0.f,0.f,0.f};
      f32x4 aV00 = z, aV01 = z, aV10 = z, aV11 = z, aV20 = z, aV21 = z, aD0 = z, aD1 = z;
#pragma unroll
      for (int ks = 0; ks < 9; ks++) {
        float hs = (ks < 8) ? hf[ks] : 1.f;
        int c2 = (ks*4 + q)*64;
        AF b0, b1f, b2, b3;
        b0.q  = *(const uint4*)&B2[(c2 +  0 + m)*8];
        b1f.q = *(const uint4*)&B2[(c2 + 16 + m)*8];
        b2.q  = *(const uint4*)&B2[(c2 + 32 + m)*8];
        b3.q  = *(const uint4*)&B2[(c2 + 48 + m)*8];
        AF a0 = mkfrag(hs, vf[0]);
        AF a1 = mkfrag(hs, vf[1]);
        AF a2 = mkfrag(hs, vf[2]);
        AF ad = mkfrag(hs, df);
        aV00 = __builtin_amdgcn_mfma_f32_16x16x32_f16(a0.v, b0.v,  aV00, 0, 0, 0);
        aV01 = __builtin_amdgcn_mfma_f32_16x16x32_f16(a0.v, b1f.v, aV01, 0, 0, 0);
        aV10 = __builtin_amdgcn_mfma_f32_16x16x32_f16(a1.v, b0.v,  aV10, 0, 0, 0);
        aV11 = __builtin_amdgcn_mfma_f32_16x16x32_f16(a1.v, b1f.v, aV11, 0, 0, 0);
        aV20 = __builtin_amdgcn_mfma_f32_16x16x32_f16(a2.v, b0.v,  aV20, 0, 0, 0);
        aV21 = __builtin_amdgcn_mfma_f32_16x16x32_f16(a2.v, b1f.v, aV21, 0, 0, 0);
        aD0  = __builtin_amdgcn_mfma_f32_16x16x32_f16(ad.v, b2.v,  aD0,  0, 0, 0);
        aD1  = __builtin_amdgcn_mfma_f32_16x16x32_f16(ad.v, b3.v,  aD1,  0, 0, 0);
      }
#pragma unroll
      for (int r = 0; r < 4; r++) {
        int et = tile*16 + q*4 + r;
        u16* mp = msgB + (size_t)et*128;
        mp[m]      = f2bf(c*aD0[r]);
        mp[16 + m] = f2bf(c*aD1[r]);
        mp[32 +      m] = f2bf(c*aV00[r]);
        mp[32 + 16 + m] = f2bf(c*aV01[r]);
        mp[64 +      m] = f2bf(c*aV10[r]);
        mp[64 + 16 + m] = f2bf(c*aV11[r]);
        mp[96 +      m] = f2bf(c*aV20[r]);
        mp[96 + 16 + m] = f2bf(c*aV21[r]);
      }
    }
  }
}

// ---- gather + mean (conv1); perm in LDS; 4-way unrolled loads ----
__global__ __launch_bounds__(256) void k_gather1(
    const u16* __restrict__ msg, const int* __restrict__ perm,
    const int* __restrict__ cur, float* __restrict__ s1,
    float* __restrict__ v1soa) {
  __shared__ int pe[2][64];
  int ln = threadIdx.x >> 7, c = threadIdx.x & 127;
  int n = blockIdx.x*2 + ln;
  int deg = min(cur[n], 64);
  if (c < 64) pe[ln][c] = perm[n*64 + c];
  __syncthreads();
  float acc = 0.f;
  int j = 0;
  for (; j + 4 <= deg; j += 4) {
    int e0 = pe[ln][j], e1 = pe[ln][j+1], e2 = pe[ln][j+2], e3 = pe[ln][j+3];
    float x0 = bf2f(msg[(size_t)e0*128 + c]);
    float x1 = bf2f(msg[(size_t)e1*128 + c]);
    float x2 = bf2f(msg[(size_t)e2*128 + c]);
    float x3 = bf2f(msg[(size_t)e3*128 + c]);
    acc += (x0 + x1) + (x2 + x3);
  }
  for (; j < deg; j++)
    acc += bf2f(msg[(size_t)pe[ln][j]*128 + c]);
  acc /= (float)max(deg, 1);
  if (c < 32) s1[n*32 + c] = acc;
  else { int i = (c-32) >> 5, w = (c-32) & 31; v1soa[i*160000 + n*32 + w] = acc; }
}

// ---- gather + mean (conv2) + self-interaction + node MLP; unrolled loads ----
__global__ __launch_bounds__(256) void k_gather2(
    const u16* __restrict__ msgA, const u16* __restrict__ msgB,
    const int* __restrict__ perm, const int* __restrict__ cur,
    const float* __restrict__ s1, const float* __restrict__ v1soa,
    const float* __restrict__ Ws, const float* __restrict__ Wv,
    const float* __restrict__ noW1, const float* __restrict__ noW2,
    float* __restrict__ s2, float* __restrict__ v2, float* __restrict__ outN) {
  __shared__ int pe[2][64];
  __shared__ float sb[2][32];
  __shared__ float hb[2][13];
  int ln = threadIdx.x >> 7, c = threadIdx.x & 127;
  int n = blockIdx.x*2 + ln;
  int deg = min(cur[n], 64);
  if (c < 64) pe[ln][c] = perm[n*64 + c];
  __syncthreads();
  float acc = 0.f;
  int j = 0;
  for (; j + 4 <= deg; j += 4) {
    int e0 = pe[ln][j], e1 = pe[ln][j+1], e2 = pe[ln][j+2], e3 = pe[ln][j+3];
    float x0 = bf2f(msgA[(size_t)e0*128 + c]) + bf2f(msgB[(size_t)e0*128 + c]);
    float x1 = bf2f(msgA[(size_t)e1*128 + c]) + bf2f(msgB[(size_t)e1*128 + c]);
    float x2 = bf2f(msgA[(size_t)e2*128 + c]) + bf2f(msgB[(size_t)e2*128 + c]);
    float x3 = bf2f(msgA[(size_t)e3*128 + c]) + bf2f(msgB[(size_t)e3*128 + c]);
    acc += (x0 + x1) + (x2 + x3);
  }
  for (; j < deg; j++) {
    int e = pe[ln][j];
    acc += bf2f(msgA[(size_t)e*128 + c]) + bf2f(msgB[(size_t)e*128 + c]);
  }
  acc /= (float)max(deg, 1);
  const float lc = 0.17677669529663687f;  // 1/sqrt(32)
  if (c < 32) {
    float ss = 0.f;
#pragma unroll 8
    for (int u = 0; u < 32; u++) ss += s1[n*32 + u] * Ws[u*32 + c];
    float val = acc + lc*ss;
    s2[n*32 + c] = val;
    sb[ln][c] = val;
  } else {
    int i = (c-32) >> 5, w = (c-32) & 31;
    float sv = 0.f;
#pragma unroll 8
    for (int u = 0; u < 32; u++) sv += v1soa[i*160000 + n*32 + u] * Wv[u*32 + w];
    v2[n*96 + w*3 + i] = acc + lc*sv;
  }
  __syncthreads();
  const float i32 = 0.17677669529663687f;
  if (c < 13) {
    float a = 0.f;
#pragma unroll 8
    for (int u = 0; u < 32; u++) a += sb[ln][u] * noW1[u*13 + c];
    hb[ln][c] = siluf(a * i32);
  }
  __syncthreads();
  const float i13 = 0.2773500981126146f;  // 1/sqrt(13)
  if (c < 13) {
    float a = 0.f;
#pragma unroll
    for (int j2 = 0; j2 < 13; j2++) a += hb[ln][j2] * noW2[j2*13 + c];
    outN[n*13 + c] = a * i13;
  }
}

// ---- edge output TP -> 5x0e; lanes = u, 2 edges per 32-lane group, 1 pair/group ----
__global__ __launch_bounds__(256) void k_e3(
    const float* __restrict__ hE, const float* __restrict__ sh,
    const float* __restrict__ s2, const float* __restrict__ v2,
    const int* __restrict__ eidx,
    const float* __restrict__ W1, const float* __restrict__ b1,
    float* __restrict__ out) {
  __shared__ uint4 WQ[640];   // [(p*5+w)*32 + u] : 8 bf16 k-values
  __shared__ float BQ[640];
  for (int t = threadIdx.x; t < 640; t += 256) {
    int u = t & 31, pw = t >> 5, p2 = pw / 5, w = pw - p2*5;
    int col = p2*160 + u*5 + w;
    const float* s = W1 + col;
    uint4 q;
    q.x = packbf2(s[0],      s[640]);
    q.y = packbf2(s[1280],   s[1920]);
    q.z = packbf2(s[2560],   s[3200]);
    q.w = packbf2(s[3840],   s[4480]);
    WQ[t] = q;
    BQ[t] = b1[col];
  }
  __syncthreads();
  const int g = threadIdx.x >> 5, tw = threadIdx.x & 31;
  const float c = 0.08838834764831845f;   // 1/sqrt(128)
  const float is3 = 0.5773502691896258f;
  for (int p = blockIdx.x*8 + g; p*2 < NE; p += gridDim.x*8) {
    int e0 = p*2, e1 = e0 + 1;
    float h0[8], h1[8];
    {
      float4 qa = *(const float4*)&hE[e0*8];
      float4 qb = *(const float4*)&hE[e0*8+4];
      h0[0]=qa.x; h0[1]=qa.y; h0[2]=qa.z; h0[3]=qa.w;
      h0[4]=qb.x; h0[5]=qb.y; h0[6]=qb.z; h0[7]=qb.w;
      float4 qc = *(const float4*)&hE[e1*8];
      float4 qd = *(const float4*)&hE[e1*8+4];
      h1[0]=qc.x; h1[1]=qc.y; h1[2]=qc.z; h1[3]=qc.w;
      h1[4]=qd.x; h1[5]=qd.y; h1[6]=qd.z; h1[7]=qd.w;
    }
    int sA = eidx[e0], dA = eidx[NE+e0];
    int sB = eidx[e1], dB = eidx[NE+e1];
    float sa0 = sh[e0*3+0], sa1 = sh[e0*3+1], sa2 = sh[e0*3+2];
    float sb0 = sh[e1*3+0], sb1 = sh[e1*3+1], sb2 = sh[e1*3+2];
    float c00 = s2[sA*32 + tw];
    float c01 = (v2[sA*96+tw*3+0]*sa0 + v2[sA*96+tw*3+1]*sa1 + v2[sA*96+tw*3+2]*sa2) * is3;
    float c02 = s2[dA*32 + tw];
    float c03 = (v2[dA*96+tw*3+0]*sa0 + v2[dA*96+tw*3+1]*sa1 + v2[dA*96+tw*3+2]*sa2) * is3;
    float c10 = s2[sB*32 + tw];
    float c11 = (v2[sB*96+tw*3+0]*sb0 + v2[sB*96+tw*3+1]*sb1 + v2[sB*96+tw*3+2]*sb2) * is3;
    float c12 = s2[dB*32 + tw];
    float c13 = (v2[dB*96+tw*3+0]*sb0 + v2[dB*96+tw*3+1]*sb1 + v2[dB*96+tw*3+2]*sb2) * is3;
    float part0[5] = {0,0,0,0,0};
    float part1[5] = {0,0,0,0,0};
#pragma unroll
    for (int pp = 0; pp < 4; pp++) {
      float cp0 = (pp==0) ? c00 : (pp==1) ? c01 : (pp==2) ? c02 : c03;
      float cp1 = (pp==0) ? c10 : (pp==1) ? c11 : (pp==2) ? c12 : c13;
#pragma unroll
      for (int w = 0; w < 5; w++) {
        int idx = (pp*5 + w)*32 + tw;
        float f[8];
        unpack8(WQ[idx], f);
        float bv = BQ[idx];
        part0[w] = fmaf(cp0, dot8f(h0, f, bv), part0[w]);
        part1[w] = fmaf(cp1, dot8f(h1, f, bv), part1[w]);
      }
    }
#pragma unroll
    for (int off = 16; off > 0; off >>= 1)
#pragma unroll
      for (int w = 0; w < 5; w++) {
        part0[w] += __shfl_xor(part0[w], off, 32);
        part1[w] += __shfl_xor(part1[w], off, 32);
      }
    float outv = 0.f;
#pragma unroll
    for (int w = 0; w < 5; w++) {
      if (tw == w)     outv = part0[w];
      if (tw == 5 + w) outv = part1[w];
    }
    if (tw < 10) out[e0*5 + tw] = c * outv;
  }
}

extern "C" void kernel_launch(void* const* d_in, const int* in_sizes, int n_in,
                              void* d_out, int out_size, void* d_ws, size_t ws_size,
                              hipStream_t stream) {
  (void)in_sizes; (void)n_in; (void)out_size; (void)ws_size;
  const float* coords = (const float*)d_in[0];
  const int*   atype  = (const int*)d_in[1];
  const int*   eidx   = (const int*)d_in[2];
  const float* emb    = (const float*)d_in[3];
  const float* ipW0 = (const float*)d_in[4];
  const float* ipb0 = (const float*)d_in[5];
  const float* ipW1 = (const float*)d_in[6];
  const float* ipb1 = (const float*)d_in[7];
  const float* lyW0 = (const float*)d_in[8];
  const float* lyb0 = (const float*)d_in[9];
  const float* lyW1 = (const float*)d_in[10];
  const float* lyb1 = (const float*)d_in[11];
  const float* lyWs = (const float*)d_in[12];
  const float* lyWv = (const float*)d_in[13];
  const float* etW0 = (const float*)d_in[14];
  const float* etb0 = (const float*)d_in[15];
  const float* etW1 = (const float*)d_in[16];
  const float* etb1 = (const float*)d_in[17];
  const float* noW1 = (const float*)d_in[18];
  const float* noW2 = (const float*)d_in[19];

  float* ws = (float*)d_ws;
  float* sh    = ws;                  // E*3
  float* h_ly  = ws + 440000;         // E*8
  float* h_et  = ws + 760000;         // E*8
  float* s1    = ws + 1240000;        // N*32
  float* v1soa = ws + 1400000;        // 3 x 160000 (SoA)
  float* s2    = ws + 1880000;        // N*32
  float* v2    = ws + 2040000;        // N*96 (AoS) -> ends 2520000
  int*   cur   = (int*)(ws + 2520000);   // N ints (poison sentinel, CAS-zeroed)
  int*   perm  = (int*)(ws + 2525000);   // N*64 ints
  u16*   msgA  = (u16*)(ws + 2845000);   // E*128 bf16
  u16*   msgB  = (u16*)(ws + 5405000);   // E*128 bf16 -> ends 7965000
  u16*   lyT   = (u16*)(ws + 7965000);   // 2*18432 f16 (pre-transposed conv2 weights)

  float* outE = (float*)d_out;            // E*5
  float* outN = (float*)d_out + NE*5;     // N*13

  k_conv1g<<<HB + 16, 256, 0, stream>>>(coords, eidx, emb, atype,
                                        ipW0, ipb0, lyW0, lyb0, etW0, etb0,
                                        ipW1, ipb1, lyW1, lyb1,
                                        sh, h_ly, h_et, cur, perm, msgA, lyT);
  k_gather1<<<NN/2, 256, 0, stream>>>(msgA, perm, cur, s1, v1soa);
  k_conv2<<<2*HB, 256, 0, stream>>>(h_ly, sh, s1, v1soa, eidx, lyT, msgA, msgB);
  k_gather2<<<NN/2, 256, 0, stream>>>(msgA, msgB, perm, cur, s1, v1soa,
                                      lyWs, lyWv, noW1, noW2, s2, v2, outN);
  k_e3<<<2500, 256, 0, stream>>>(h_et, sh, s2, v2, eidx, etW1, etb1, outE);
}